// Round 2
// baseline (11822.962 us; speedup 1.0000x reference)
//
#include <hip/hip_runtime.h>
#include <cmath>

#define T_STEPS 128
#define B_SZ    4
#define L_DIM   6368
#define L4V     1592      // L_DIM/4
#define H1_DIM  2133
#define H2_DIM  4250
#define NBLK    256
#define NMV     255
#define ROWS_PB 25        // rows per matvec block (255*25 = 6375 >= 6368)

// ws layout (float offsets)
#define OFF_THA  0
#define OFF_THB  25472
#define OFF_W1T  50944     // 2 slots * 16384
#define OFF_W2T  83712     // 2 slots * 8192
#define OFF_DIFF 100096    // 2 slots * 68
#define OFF_BAR  100232    // 1 (unsigned)
#define OFF_H1   100236    // 4*2133
#define OFF_H2   108768    // 4*4250  (end: 125768 floats = 503 KB)

__device__ inline void fma4(float4& acc, float4 a, float4 t0, float4 t1, float4 t2, float4 t3) {
    acc.x += a.x*t0.x + a.y*t1.x + a.z*t2.x + a.w*t3.x;
    acc.y += a.x*t0.y + a.y*t1.y + a.z*t2.y + a.w*t3.y;
    acc.z += a.x*t0.z + a.y*t1.z + a.z*t2.z + a.w*t3.z;
    acc.w += a.x*t0.w + a.y*t1.w + a.z*t2.w + a.w*t3.w;
}

__device__ inline float4 red4(float4 v) {
    #pragma unroll
    for (int off = 32; off; off >>= 1) {
        v.x += __shfl_xor(v.x, off);
        v.y += __shfl_xor(v.y, off);
        v.z += __shfl_xor(v.z, off);
        v.w += __shfl_xor(v.w, off);
    }
    return v;
}

// scatter w1/w2 regions of theta' transposed for the root MLP's coalesced reads
__device__ inline void aux_write(float4* w1o, float4* w2o, int r, float4 v) {
    if (r >= 128 && r < 4224) {
        int j = r - 128;                   // j = r_mlp*64 + k
        w1o[(j & 63)*64 + (j >> 6)] = v;   // [k][r_mlp] x 4 batches
    } else if (r >= 4288 && r < 6336) {
        int j = r - 4288;
        w2o[(j & 63)*32 + (j >> 6)] = v;
    }
}

__device__ inline float softplusf(float x) {
    return (x > 20.f) ? x : log1pf(expf(x));
}

__device__ inline void grid_barrier(unsigned* bar, unsigned target) {
    __syncthreads();
    if (threadIdx.x == 0) {
        __threadfence();  // release our writes device-wide
        __hip_atomic_fetch_add(bar, 1u, __ATOMIC_RELEASE, __HIP_MEMORY_SCOPE_AGENT);
        while (__hip_atomic_load(bar, __ATOMIC_ACQUIRE, __HIP_MEMORY_SCOPE_AGENT) < target) {
            __builtin_amdgcn_s_sleep(2);
        }
        __threadfence();  // acquire: invalidate caches before reading others' writes
    }
    __syncthreads();
}

__global__ __launch_bounds__(512)
void seq_kernel(const float* __restrict__ A,
                const float* __restrict__ Bm,
                const float* __restrict__ xs,
                const float* __restrict__ ts,
                float* __restrict__ outp,
                float* thetaA, float* thetaB,
                float* w1t, float* w2t, float* diffb,
                unsigned* bar)
{
    __shared__ float4 sred[2][13][8];   // [row-group][row][wave]
    const int blk = blockIdx.x;
    const int tid = threadIdx.x;
    const int w = tid >> 6, l = tid & 63;
    const float4* A4 = (const float4*)A;

    if (blk < NMV) {
        // --------- matvec blocks: waves split k, theta in registers ---------
        const int r0 = blk * ROWS_PB;
        const int nrows = min(ROWS_PB, L_DIM - r0);   // 25, except last block 18
        const int jc0 = tid;
        const int jc1 = tid + 512;
        const int jc2 = tid + 1024;
        const int jc3 = tid + 1536;
        const bool v3 = (jc3 < L4V);                  // only tid<56 has a 4th k-chunk

        for (int it = 0; it <= T_STEPS; ++it) {
            if (it < T_STEPS) {
                const float4* th4 = (const float4*)((it & 1) ? thetaB : thetaA);
                float4* thOut4 = (float4*)((it & 1) ? thetaA : thetaB);
                float4* w1o = (float4*)(w1t + ((it + 1) & 1) * 16384);
                float4* w2o = (float4*)(w2t + ((it + 1) & 1) * 8192);
                const float* dvec = diffb + (it & 1) * 68;

                // theta slice -> registers (coalesced 64B/thread per chunk)
                float4 th[16];
                {
                    const float4* p0 = th4 + 4*jc0;
                    th[0] = p0[0]; th[1] = p0[1]; th[2] = p0[2]; th[3] = p0[3];
                    const float4* p1 = th4 + 4*jc1;
                    th[4] = p1[0]; th[5] = p1[1]; th[6] = p1[2]; th[7] = p1[3];
                    const float4* p2 = th4 + 4*jc2;
                    th[8] = p2[0]; th[9] = p2[1]; th[10] = p2[2]; th[11] = p2[3];
                    if (v3) {
                        const float4* p3 = th4 + 4*jc3;
                        th[12] = p3[0]; th[13] = p3[1]; th[14] = p3[2]; th[15] = p3[3];
                    }
                }

                #pragma unroll
                for (int g = 0; g < 2; ++g) {
                    const int base = r0 + g*13;
                    float4 acc[13];
                    #pragma unroll
                    for (int r = 0; r < 13; ++r) acc[r] = make_float4(0.f,0.f,0.f,0.f);

                    #pragma unroll
                    for (int c = 0; c < 4; ++c) {
                        if (c == 3 && !v3) continue;
                        const int jc = tid + c*512;
                        const float4* abase = A4 + (size_t)base * L4V + jc;
                        #pragma unroll
                        for (int r = 0; r < 13; ++r) {
                            if (base + r < L_DIM) {        // block-uniform scalar guard
                                float4 av = abase[(size_t)r * L4V];
                                fma4(acc[r], av, th[4*c], th[4*c+1], th[4*c+2], th[4*c+3]);
                            }
                        }
                    }
                    #pragma unroll
                    for (int r = 0; r < 13; ++r) {
                        float4 s = red4(acc[r]);
                        if (l == 0) sred[g][r][w] = s;
                    }
                }
                __syncthreads();
                if (tid < nrows) {
                    const int g = (tid < 13) ? 0 : 1;
                    const int ri = tid - g*13;
                    float4 v = sred[g][ri][0];
                    #pragma unroll
                    for (int q = 1; q < 8; ++q) {
                        float4 s = sred[g][ri][q];
                        v.x += s.x; v.y += s.y; v.z += s.z; v.w += s.w;
                    }
                    const int row = r0 + tid;
                    const float* bmr = Bm + (size_t)row * 17;
                    #pragma unroll
                    for (int k = 0; k < 17; ++k) {
                        float bv = bmr[k];
                        v.x += bv * dvec[k];
                        v.y += bv * dvec[17 + k];
                        v.z += bv * dvec[34 + k];
                        v.w += bv * dvec[51 + k];
                    }
                    thOut4[row] = v;
                    aux_write(w1o, w2o, row, v);
                }
            }
            if (it < T_STEPS) grid_barrier(bar, (unsigned)(NBLK * (it + 1)));
        }
    } else {
        // --------- root block: root_apply_{it-1} + prepare diff_{it+1} ---------
        const int b = w;  // waves 0..3 = batches; 4..7 idle
        for (int it = 0; it <= T_STEPS; ++it) {
            float xv = 0.f;
            if (b < B_SZ) {
                if (it >= 1) {
                    const int t = it - 1;
                    const float* th  = (it & 1) ? thetaB : thetaA;  // theta^{it}
                    const float* w1c = w1t + (it & 1) * 16384;
                    const float* w2c = w2t + (it & 1) * 8192;
                    float tcur = ts[b*T_STEPS + t];
                    float tin = (t >= 1) ? (2.f*tcur - ts[b*T_STEPS + t - 1]) : tcur;
                    // h0 = relu(w0*tin + c0)
                    float h0 = fmaxf(th[l*4 + b] * tin + th[(64 + l)*4 + b], 0.f);
                    // h1 = relu(w1 @ h0 + c1)
                    float a1v = th[(4224 + l)*4 + b];
                    #pragma unroll
                    for (int k = 0; k < 64; ++k)
                        a1v += w1c[(k*64 + l)*4 + b] * __shfl(h0, k);
                    float h1 = fmaxf(a1v, 0.f);
                    // o = w2 @ h1 + c2  (32 outputs, lanes 0..31)
                    float ov = th[(6336 + (l & 31))*4 + b];
                    #pragma unroll
                    for (int k = 0; k < 64; ++k)
                        ov += w2c[(k*32 + (l & 31))*4 + b] * __shfl(h1, k);
                    if (l < 32) {
                        xv = (l < 16) ? tanhf(ov) : softplusf(ov);
                        outp[(b*T_STEPS + t)*32 + l] = xv;
                    }
                }
                if (it + 1 <= T_STEPS - 1) {
                    float* dd = diffb + ((it + 1) & 1) * 68 + b*17;
                    if (l < 16) {
                        float xprev = (it >= 1) ? xv : xs[(size_t)(b*T_STEPS)*16 + l];
                        dd[1 + l] = xs[(size_t)(b*T_STEPS + it + 1)*16 + l] - xprev;
                    } else if (l == 16) {
                        dd[0] = ts[b*T_STEPS + it + 1] - ts[b*T_STEPS + it];
                    }
                }
            }
            if (it < T_STEPS) grid_barrier(bar, (unsigned)(NBLK * (it + 1)));
        }
    }
}

// h1 = relu(W1 @ xs0 + b1), plus zero diff slots and barrier counter
__global__ __launch_bounds__(256)
void init_h1(const float* __restrict__ xs, const float* __restrict__ W1,
             const float* __restrict__ b1, float* __restrict__ h1ws,
             float* __restrict__ diffb)
{
    const int b = blockIdx.y;
    const int r = blockIdx.x * 256 + threadIdx.x;
    if (blockIdx.x == 0 && b == 0 && threadIdx.x < 137)
        diffb[threadIdx.x] = 0.f;  // 136 diff floats + barrier counter (bit pattern 0)
    if (r < H1_DIM) {
        const float* wr = W1 + r*16;
        const float* x0 = xs + (size_t)b * T_STEPS * 16;
        float s = b1[r];
        #pragma unroll
        for (int k = 0; k < 16; ++k) s += wr[k] * x0[k];
        h1ws[b*H1_DIM + r] = fmaxf(s, 0.f);
    }
}

// out[b][r] = maybe_relu(sum_k W[r][k]*in[b][k] + bias[r]); ilv => out[r*4+b]
__global__ __launch_bounds__(256)
void init_mm(const float* __restrict__ W, const float* __restrict__ bias,
             const float* __restrict__ in, float* __restrict__ outp,
             int rows, int K, int dorelu, int ilv)
{
    const int w = threadIdx.x >> 6, l = threadIdx.x & 63;
    const int gw = blockIdx.x * 4 + w;
    const int nw = gridDim.x * 4;
    for (int r = gw; r < rows; r += nw) {
        const float* wr = W + (size_t)r * K;
        float a0 = 0.f, a1 = 0.f, a2 = 0.f, a3 = 0.f;
        for (int k = l; k < K; k += 64) {
            float wv = wr[k];
            a0 += wv * in[k];
            a1 += wv * in[K + k];
            a2 += wv * in[2*K + k];
            a3 += wv * in[3*K + k];
        }
        #pragma unroll
        for (int off = 32; off; off >>= 1) {
            a0 += __shfl_xor(a0, off);
            a1 += __shfl_xor(a1, off);
            a2 += __shfl_xor(a2, off);
            a3 += __shfl_xor(a3, off);
        }
        if (l == 0) {
            float bb = bias[r];
            a0 += bb; a1 += bb; a2 += bb; a3 += bb;
            if (dorelu) {
                a0 = fmaxf(a0, 0.f); a1 = fmaxf(a1, 0.f);
                a2 = fmaxf(a2, 0.f); a3 = fmaxf(a3, 0.f);
            }
            if (ilv) {
                outp[r*4 + 0] = a0; outp[r*4 + 1] = a1;
                outp[r*4 + 2] = a2; outp[r*4 + 3] = a3;
            } else {
                outp[0*rows + r] = a0; outp[1*rows + r] = a1;
                outp[2*rows + r] = a2; outp[3*rows + r] = a3;
            }
        }
    }
}

extern "C" void kernel_launch(void* const* d_in, const int* in_sizes, int n_in,
                              void* d_out, int out_size, void* d_ws, size_t ws_size,
                              hipStream_t stream) {
    const float* xs = (const float*)d_in[0];
    const float* ts = (const float*)d_in[1];
    const float* A  = (const float*)d_in[2];
    const float* Bm = (const float*)d_in[3];
    const float* W1 = (const float*)d_in[4];
    const float* b1 = (const float*)d_in[5];
    const float* W2 = (const float*)d_in[6];
    const float* b2 = (const float*)d_in[7];
    const float* W3 = (const float*)d_in[8];
    const float* b3 = (const float*)d_in[9];
    // d_in[10] = seed: unused (FORCING_PROB == 1.0 makes the RNG dead code)
    float* outp = (float*)d_out;
    float* wsf  = (float*)d_ws;

    float* thetaA = wsf + OFF_THA;
    float* thetaB = wsf + OFF_THB;
    float* w1t    = wsf + OFF_W1T;
    float* w2t    = wsf + OFF_W2T;
    float* diffb  = wsf + OFF_DIFF;
    unsigned* bar = (unsigned*)(wsf + OFF_BAR);
    float* h1ws   = wsf + OFF_H1;
    float* h2ws   = wsf + OFF_H2;

    init_h1<<<dim3((H1_DIM + 255)/256, B_SZ), 256, 0, stream>>>(xs, W1, b1, h1ws, diffb);
    init_mm<<<dim3(128), 256, 0, stream>>>(W2, b2, h1ws, h2ws, H2_DIM, H1_DIM, 1, 0);
    init_mm<<<dim3(256), 256, 0, stream>>>(W3, b3, h2ws, thetaA, L_DIM, H2_DIM, 0, 1);
    seq_kernel<<<dim3(NBLK), dim3(512), 0, stream>>>(A, Bm, xs, ts, outp,
                                                     thetaA, thetaB, w1t, w2t, diffb, bar);
}

// Round 3
// 7199.163 us; speedup vs baseline: 1.6423x; 1.6423x over previous
//
#include <hip/hip_runtime.h>
#include <cmath>

#define T_STEPS 128
#define B_SZ    4
#define L_DIM   6368
#define LP4     1592      // float4s per theta plane (6368/4)
#define HP4     796       // float4s per half plane
#define H1_DIM  2133
#define H2_DIM  4250
#define NBLK    256
#define NMV     255

// ws layout (float offsets)
#define OFF_THA  0
#define OFF_THB  25472
#define OFF_DIFF 50944     // 2 slots * 68
#define OFF_BAR  51080     // 1 (unsigned)
#define OFF_H1   51084     // 4*2133
#define OFF_H2   59616     // 4*4250 (end: 76616 floats = 306 KB)

// acc.{x,y,z,w} = batches 0..3; a = 4 consecutive k of one A row;
// t0..t3 = same 4 k's of theta planes (batch 0..3)
__device__ inline void fmadot(float4& acc, float4 a, float4 t0, float4 t1, float4 t2, float4 t3) {
    acc.x += a.x*t0.x + a.y*t0.y + a.z*t0.z + a.w*t0.w;
    acc.y += a.x*t1.x + a.y*t1.y + a.z*t1.z + a.w*t1.w;
    acc.z += a.x*t2.x + a.y*t2.y + a.z*t2.z + a.w*t2.w;
    acc.w += a.x*t3.x + a.y*t3.y + a.z*t3.z + a.w*t3.w;
}

__device__ inline float4 red4(float4 v) {
    #pragma unroll
    for (int off = 32; off; off >>= 1) {
        v.x += __shfl_xor(v.x, off);
        v.y += __shfl_xor(v.y, off);
        v.z += __shfl_xor(v.z, off);
        v.w += __shfl_xor(v.w, off);
    }
    return v;
}

__device__ inline float softplusf(float x) {
    return (x > 20.f) ? x : log1pf(expf(x));
}

__device__ inline void grid_barrier(unsigned* bar, unsigned target) {
    __syncthreads();
    if (threadIdx.x == 0) {
        __threadfence();
        __hip_atomic_fetch_add(bar, 1u, __ATOMIC_RELEASE, __HIP_MEMORY_SCOPE_AGENT);
        while (__hip_atomic_load(bar, __ATOMIC_ACQUIRE, __HIP_MEMORY_SCOPE_AGENT) < target) {
            __builtin_amdgcn_s_sleep(2);
        }
        __threadfence();
    }
    __syncthreads();
}

__global__ __launch_bounds__(512, 2)
void seq_kernel(const float* __restrict__ A,
                const float* __restrict__ Bm,
                const float* __restrict__ xs,
                const float* __restrict__ ts,
                float* __restrict__ outp,
                float* thetaA, float* thetaB, float* diffb,
                unsigned* bar)
{
    __shared__ float4 sth[4 * HP4];   // 4 half-planes, 50.9 KB, conflict-free b128 reads
    const int blk = blockIdx.x;
    const int tid = threadIdx.x;
    const int w = tid >> 6, l = tid & 63;
    const float4* A4 = (const float4*)A;

    if (blk < NMV) {
        // ---- matvec blocks: wave owns 3(+1) rows, sweeps full k via LDS planes ----
        const int r0 = (blk * L_DIM) / NMV;
        const int r1 = ((blk + 1) * L_DIM) / NMV;
        const int nrows = r1 - r0;                 // 24 or 25
        const int row0 = r0 + w;
        const int row1 = r0 + w + 8;
        const int row2 = r0 + w + 16;
        const int row3 = r0 + 24;                  // only wave 0 when nrows==25
        const bool has3 = (w == 0) && (nrows == 25);

        for (int it = 0; it <= T_STEPS; ++it) {
            if (it < T_STEPS) {
                const float* thIn = (it & 1) ? thetaB : thetaA;
                float* thOut = (it & 1) ? thetaA : thetaB;
                const float4* thIn4 = (const float4*)thIn;
                const float* dvec = diffb + (it & 1) * 68;

                float4 acc0 = make_float4(0.f,0.f,0.f,0.f);
                float4 acc1 = make_float4(0.f,0.f,0.f,0.f);
                float4 acc2 = make_float4(0.f,0.f,0.f,0.f);
                float4 acc3 = make_float4(0.f,0.f,0.f,0.f);

                for (int h = 0; h < 2; ++h) {
                    __syncthreads();
                    #pragma unroll
                    for (int p = 0; p < 4; ++p) {
                        const float4* src = thIn4 + p * LP4 + h * HP4;
                        for (int u = tid; u < HP4; u += 512) sth[p * HP4 + u] = src[u];
                    }
                    __syncthreads();
                    const float4* a0 = A4 + (size_t)row0 * LP4 + h * HP4;
                    const float4* a1 = A4 + (size_t)row1 * LP4 + h * HP4;
                    const float4* a2 = A4 + (size_t)row2 * LP4 + h * HP4;
                    const float4* a3 = A4 + (size_t)row3 * LP4 + h * HP4;

                    if (has3) {
                        #pragma unroll 4
                        for (int m = 0; m < 12; ++m) {
                            const int g = l + (m << 6);
                            float4 t0 = sth[g], t1 = sth[HP4 + g], t2 = sth[2*HP4 + g], t3 = sth[3*HP4 + g];
                            float4 v0 = a0[g], v1 = a1[g], v2 = a2[g], v3 = a3[g];
                            fmadot(acc0, v0, t0, t1, t2, t3);
                            fmadot(acc1, v1, t0, t1, t2, t3);
                            fmadot(acc2, v2, t0, t1, t2, t3);
                            fmadot(acc3, v3, t0, t1, t2, t3);
                        }
                        if (l < HP4 - 768) {   // tail: g in [768,796)
                            const int g = l + 768;
                            float4 t0 = sth[g], t1 = sth[HP4 + g], t2 = sth[2*HP4 + g], t3 = sth[3*HP4 + g];
                            float4 v0 = a0[g], v1 = a1[g], v2 = a2[g], v3 = a3[g];
                            fmadot(acc0, v0, t0, t1, t2, t3);
                            fmadot(acc1, v1, t0, t1, t2, t3);
                            fmadot(acc2, v2, t0, t1, t2, t3);
                            fmadot(acc3, v3, t0, t1, t2, t3);
                        }
                    } else {
                        #pragma unroll 4
                        for (int m = 0; m < 12; ++m) {
                            const int g = l + (m << 6);
                            float4 t0 = sth[g], t1 = sth[HP4 + g], t2 = sth[2*HP4 + g], t3 = sth[3*HP4 + g];
                            float4 v0 = a0[g], v1 = a1[g], v2 = a2[g];
                            fmadot(acc0, v0, t0, t1, t2, t3);
                            fmadot(acc1, v1, t0, t1, t2, t3);
                            fmadot(acc2, v2, t0, t1, t2, t3);
                        }
                        if (l < HP4 - 768) {
                            const int g = l + 768;
                            float4 t0 = sth[g], t1 = sth[HP4 + g], t2 = sth[2*HP4 + g], t3 = sth[3*HP4 + g];
                            float4 v0 = a0[g], v1 = a1[g], v2 = a2[g];
                            fmadot(acc0, v0, t0, t1, t2, t3);
                            fmadot(acc1, v1, t0, t1, t2, t3);
                            fmadot(acc2, v2, t0, t1, t2, t3);
                        }
                    }
                }

                // fold Bm @ diff into partial sums (lanes 0..16), reduced by red4
                if (l < 17) {
                    float d0 = dvec[l], d1 = dvec[17+l], d2 = dvec[34+l], d3 = dvec[51+l];
                    float bv;
                    bv = Bm[row0*17 + l]; acc0.x += bv*d0; acc0.y += bv*d1; acc0.z += bv*d2; acc0.w += bv*d3;
                    bv = Bm[row1*17 + l]; acc1.x += bv*d0; acc1.y += bv*d1; acc1.z += bv*d2; acc1.w += bv*d3;
                    bv = Bm[row2*17 + l]; acc2.x += bv*d0; acc2.y += bv*d1; acc2.z += bv*d2; acc2.w += bv*d3;
                    if (has3) {
                        bv = Bm[row3*17 + l]; acc3.x += bv*d0; acc3.y += bv*d1; acc3.z += bv*d2; acc3.w += bv*d3;
                    }
                }
                acc0 = red4(acc0); acc1 = red4(acc1); acc2 = red4(acc2);
                if (has3) acc3 = red4(acc3);
                if (l == 0) {
                    thOut[row0] = acc0.x; thOut[L_DIM + row0] = acc0.y;
                    thOut[2*L_DIM + row0] = acc0.z; thOut[3*L_DIM + row0] = acc0.w;
                    thOut[row1] = acc1.x; thOut[L_DIM + row1] = acc1.y;
                    thOut[2*L_DIM + row1] = acc1.z; thOut[3*L_DIM + row1] = acc1.w;
                    thOut[row2] = acc2.x; thOut[L_DIM + row2] = acc2.y;
                    thOut[2*L_DIM + row2] = acc2.z; thOut[3*L_DIM + row2] = acc2.w;
                    if (has3) {
                        thOut[row3] = acc3.x; thOut[L_DIM + row3] = acc3.y;
                        thOut[2*L_DIM + row3] = acc3.z; thOut[3*L_DIM + row3] = acc3.w;
                    }
                }
            }
            if (it < T_STEPS) grid_barrier(bar, (unsigned)(NBLK * (it + 1)));
        }
    } else {
        // ---- root block: root_apply_{it-1} + prepare diff_{it+1} ----
        const int b = w;   // waves 0..3 = batches
        for (int it = 0; it <= T_STEPS; ++it) {
            float xv = 0.f;
            if (b < B_SZ) {
                if (it >= 1) {
                    const int t = it - 1;
                    const float* th = ((it & 1) ? thetaB : thetaA) + b * L_DIM;  // batch plane
                    float tcur = ts[b*T_STEPS + t];
                    float tin = (t >= 1) ? (2.f*tcur - ts[b*T_STEPS + t - 1]) : tcur;
                    // h0 = relu(w0*tin + c0)
                    float h0 = fmaxf(th[l] * tin + th[64 + l], 0.f);
                    // h1 = relu(w1 @ h0 + c1): lane l's weight row is contiguous in the plane
                    float a1v = th[4224 + l];
                    const float4* w1r = (const float4*)(th + 128 + 64*l);
                    #pragma unroll
                    for (int j = 0; j < 16; ++j) {
                        float4 wv = w1r[j];
                        a1v += wv.x*__shfl(h0, 4*j)   + wv.y*__shfl(h0, 4*j+1)
                             + wv.z*__shfl(h0, 4*j+2) + wv.w*__shfl(h0, 4*j+3);
                    }
                    float h1 = fmaxf(a1v, 0.f);
                    // o = w2 @ h1 + c2 (32 outputs; lanes 32..63 duplicate harmlessly)
                    float ov = th[6336 + (l & 31)];
                    const float4* w2r = (const float4*)(th + 4288 + 64*(l & 31));
                    #pragma unroll
                    for (int j = 0; j < 16; ++j) {
                        float4 wv = w2r[j];
                        ov += wv.x*__shfl(h1, 4*j)   + wv.y*__shfl(h1, 4*j+1)
                            + wv.z*__shfl(h1, 4*j+2) + wv.w*__shfl(h1, 4*j+3);
                    }
                    if (l < 32) {
                        xv = (l < 16) ? tanhf(ov) : softplusf(ov);
                        outp[(b*T_STEPS + t)*32 + l] = xv;
                    }
                }
                if (it + 1 <= T_STEPS - 1) {
                    float* dd = diffb + ((it + 1) & 1) * 68 + b*17;
                    if (l < 16) {
                        float xprev = (it >= 1) ? xv : xs[(size_t)(b*T_STEPS)*16 + l];
                        dd[1 + l] = xs[(size_t)(b*T_STEPS + it + 1)*16 + l] - xprev;
                    } else if (l == 16) {
                        dd[0] = ts[b*T_STEPS + it + 1] - ts[b*T_STEPS + it];
                    }
                }
            }
            if (it < T_STEPS) grid_barrier(bar, (unsigned)(NBLK * (it + 1)));
        }
    }
}

// h1 = relu(W1 @ xs0 + b1), plus zero diff slots and barrier counter
__global__ __launch_bounds__(256)
void init_h1(const float* __restrict__ xs, const float* __restrict__ W1,
             const float* __restrict__ b1, float* __restrict__ h1ws,
             float* __restrict__ diffb)
{
    const int b = blockIdx.y;
    const int r = blockIdx.x * 256 + threadIdx.x;
    if (blockIdx.x == 0 && b == 0 && threadIdx.x < 137)
        diffb[threadIdx.x] = 0.f;  // 136 diff floats + barrier counter
    if (r < H1_DIM) {
        const float* wr = W1 + r*16;
        const float* x0 = xs + (size_t)b * T_STEPS * 16;
        float s = b1[r];
        #pragma unroll
        for (int k = 0; k < 16; ++k) s += wr[k] * x0[k];
        h1ws[b*H1_DIM + r] = fmaxf(s, 0.f);
    }
}

// out[b*rows + r] = maybe_relu(sum_k W[r][k]*in[b*K+k] + bias[r])   (plane output)
__global__ __launch_bounds__(256)
void init_mm(const float* __restrict__ W, const float* __restrict__ bias,
             const float* __restrict__ in, float* __restrict__ outp,
             int rows, int K, int dorelu)
{
    const int w = threadIdx.x >> 6, l = threadIdx.x & 63;
    const int gw = blockIdx.x * 4 + w;
    const int nw = gridDim.x * 4;
    for (int r = gw; r < rows; r += nw) {
        const float* wr = W + (size_t)r * K;
        float a0 = 0.f, a1 = 0.f, a2 = 0.f, a3 = 0.f;
        for (int k = l; k < K; k += 64) {
            float wv = wr[k];
            a0 += wv * in[k];
            a1 += wv * in[K + k];
            a2 += wv * in[2*K + k];
            a3 += wv * in[3*K + k];
        }
        #pragma unroll
        for (int off = 32; off; off >>= 1) {
            a0 += __shfl_xor(a0, off);
            a1 += __shfl_xor(a1, off);
            a2 += __shfl_xor(a2, off);
            a3 += __shfl_xor(a3, off);
        }
        if (l == 0) {
            float bb = bias[r];
            a0 += bb; a1 += bb; a2 += bb; a3 += bb;
            if (dorelu) {
                a0 = fmaxf(a0, 0.f); a1 = fmaxf(a1, 0.f);
                a2 = fmaxf(a2, 0.f); a3 = fmaxf(a3, 0.f);
            }
            outp[0*rows + r] = a0; outp[1*rows + r] = a1;
            outp[2*rows + r] = a2; outp[3*rows + r] = a3;
        }
    }
}

extern "C" void kernel_launch(void* const* d_in, const int* in_sizes, int n_in,
                              void* d_out, int out_size, void* d_ws, size_t ws_size,
                              hipStream_t stream) {
    const float* xs = (const float*)d_in[0];
    const float* ts = (const float*)d_in[1];
    const float* A  = (const float*)d_in[2];
    const float* Bm = (const float*)d_in[3];
    const float* W1 = (const float*)d_in[4];
    const float* b1 = (const float*)d_in[5];
    const float* W2 = (const float*)d_in[6];
    const float* b2 = (const float*)d_in[7];
    const float* W3 = (const float*)d_in[8];
    const float* b3 = (const float*)d_in[9];
    // d_in[10] = seed: unused (FORCING_PROB == 1.0 makes the RNG dead code)
    float* outp = (float*)d_out;
    float* wsf  = (float*)d_ws;

    float* thetaA = wsf + OFF_THA;
    float* thetaB = wsf + OFF_THB;
    float* diffb  = wsf + OFF_DIFF;
    unsigned* bar = (unsigned*)(wsf + OFF_BAR);
    float* h1ws   = wsf + OFF_H1;
    float* h2ws   = wsf + OFF_H2;

    init_h1<<<dim3((H1_DIM + 255)/256, B_SZ), 256, 0, stream>>>(xs, W1, b1, h1ws, diffb);
    init_mm<<<dim3(128), 256, 0, stream>>>(W2, b2, h1ws, h2ws, H2_DIM, H1_DIM, 1);
    init_mm<<<dim3(256), 256, 0, stream>>>(W3, b3, h2ws, thetaA, L_DIM, H2_DIM, 0);
    seq_kernel<<<dim3(NBLK), dim3(512), 0, stream>>>(A, Bm, xs, ts, outp,
                                                     thetaA, thetaB, diffb, bar);
}